// Round 2
// baseline (602.364 us; speedup 1.0000x reference)
//
#include <hip/hip_runtime.h>
#include <hip/hip_bf16.h>

// Problem constants
#define BB 4
#define TT 2048
#define CCH 1024
#define NHH 16
#define HSS 64
#define MROWS (BB * TT)            // 8192
#define QKV_ELEMS (64 * 2048 * 64) // per-tensor elems = 8388608

typedef __attribute__((ext_vector_type(8))) short short8;
typedef __attribute__((ext_vector_type(4))) float f32x4;

static __device__ __forceinline__ unsigned short bf16_of(float f) {
  union { float f; unsigned u; } v; v.f = f;
  unsigned u = v.u;
  return (unsigned short)((u + 0x7FFFu + ((u >> 16) & 1u)) >> 16);
}

// ---------------- cast kernels ----------------
__global__ __launch_bounds__(256) void cast_f32_bf16(const float* __restrict__ in,
                                                     unsigned short* __restrict__ out, int n) {
  int i = (blockIdx.x * 256 + threadIdx.x) * 4;
  if (i < n) {
    float4 f = *reinterpret_cast<const float4*>(in + i);
    ushort4 o;
    o.x = bf16_of(f.x); o.y = bf16_of(f.y); o.z = bf16_of(f.z); o.w = bf16_of(f.w);
    *reinterpret_cast<ushort4*>(out + i) = o;
  }
}

// in: [K][N] f32 row-major -> out: [N][K] bf16 row-major
__global__ __launch_bounds__(256) void transpose_cast(const float* __restrict__ in,
                                                      unsigned short* __restrict__ out,
                                                      int K, int N) {
  int idx = blockIdx.x * 256 + threadIdx.x;
  if (idx < K * N) {
    int k = idx / N;
    int n = idx - k * N;
    out[(size_t)n * K + k] = bf16_of(in[idx]);
  }
}

// ---------------- GEMM: C = A[M,K] @ Bt[N,K]^T + bias ----------------
// MODE 0: write fp32 out[M,N]
// MODE 1: QKV epilogue -> bf16 q/k in [B*NH][T][HS]; v transposed -> [B*NH][HS][T]
template <int MODE>
__global__ __launch_bounds__(256) void gemm_bt(const unsigned short* __restrict__ A,
                                               const unsigned short* __restrict__ Bt,
                                               const float* __restrict__ bias,
                                               float* __restrict__ outF,
                                               unsigned short* __restrict__ outQKV,
                                               int M, int N, int K) {
  __shared__ unsigned short As[128 * 32];
  __shared__ unsigned short Bs[128 * 32];
  int tid = threadIdx.x;
  int w = tid >> 6, lane = tid & 63;
  int g = lane >> 4, r16 = lane & 15;
  int wr = w >> 1, wc = w & 1;
  int m0 = blockIdx.y * 128, n0 = blockIdx.x * 128;
  int lrow = lane >> 2;           // 0..15 row within 16-row staging group
  int lcol = (lane & 3) * 8;      // ushort offset (16B chunks)

  f32x4 zero = {0.f, 0.f, 0.f, 0.f};
  f32x4 acc[4][4];
#pragma unroll
  for (int i = 0; i < 4; ++i)
#pragma unroll
    for (int n = 0; n < 4; ++n) acc[i][n] = zero;

  for (int kt = 0; kt < K; kt += 32) {
#pragma unroll
    for (int c = 0; c < 2; ++c) {
      int rg = w * 32 + c * 16;   // wave-uniform row-group base
      __builtin_amdgcn_global_load_lds(
          (const __attribute__((address_space(1))) void*)(&A[(size_t)(m0 + rg + lrow) * K + kt + lcol]),
          (__attribute__((address_space(3))) void*)(&As[rg * 32]), 16, 0, 0);
      __builtin_amdgcn_global_load_lds(
          (const __attribute__((address_space(1))) void*)(&Bt[(size_t)(n0 + rg + lrow) * K + kt + lcol]),
          (__attribute__((address_space(3))) void*)(&Bs[rg * 32]), 16, 0, 0);
    }
    __syncthreads();
    short8 af[4], bfr[4];
#pragma unroll
    for (int i = 0; i < 4; ++i)
      af[i] = *reinterpret_cast<const short8*>(&As[(wr * 64 + i * 16 + r16) * 32 + g * 8]);
#pragma unroll
    for (int i = 0; i < 4; ++i)
      bfr[i] = *reinterpret_cast<const short8*>(&Bs[(wc * 64 + i * 16 + r16) * 32 + g * 8]);
#pragma unroll
    for (int i = 0; i < 4; ++i)
#pragma unroll
      for (int n = 0; n < 4; ++n)
        acc[i][n] = __builtin_amdgcn_mfma_f32_16x16x32_bf16(af[i], bfr[n], acc[i][n], 0, 0, 0);
    __syncthreads();
  }

#pragma unroll
  for (int i = 0; i < 4; ++i)
#pragma unroll
    for (int n = 0; n < 4; ++n)
#pragma unroll
      for (int j = 0; j < 4; ++j) {
        int row = m0 + wr * 64 + i * 16 + g * 4 + j;
        int col = n0 + wc * 64 + n * 16 + r16;
        float val = acc[i][n][j] + bias[col];
        if (MODE == 0) {
          outF[(size_t)row * N + col] = val;
        } else {
          int which = col >> 10, c = col & 1023;
          int h = c >> 6, d = c & 63;
          int b = row >> 11, t = row & 2047;
          if (which == 2) {
            // V transposed: [bh][d][t]
            outQKV[2 * (size_t)QKV_ELEMS +
                   (((size_t)(b * 16 + h) * 64 + d) * 2048 + t)] = bf16_of(val);
          } else {
            outQKV[(size_t)which * QKV_ELEMS +
                   (((size_t)(b * 16 + h) * 2048 + t) * 64 + d)] = bf16_of(val);
          }
        }
      }
}

// ---------------- causal flash attention (barrier-free) ----------------
// Q,K: [B*NH][T][HS] bf16.  Vt: [B*NH][HS][T] bf16.  Y: [B][T][C] bf16.
__global__ __launch_bounds__(256) void attn_kernel(const unsigned short* __restrict__ Qm,
                                                   const unsigned short* __restrict__ Km,
                                                   const unsigned short* __restrict__ Vt,
                                                   unsigned short* __restrict__ Y) {
  __shared__ unsigned short P[4][16][32]; // per-wave private P tile (no barriers needed)

  int tid = threadIdx.x;
  int w = tid >> 6, lane = tid & 63;
  int g = lane >> 4, r16 = lane & 15;
  int bh = blockIdx.y;            // 0..63
  int qw0 = blockIdx.x * 64 + w * 16;
  const size_t base = (size_t)bh * TT * HSS;   // Q,K: [t][d]
  const size_t vbase = (size_t)bh * HSS * TT;  // Vt: [d][t]

  short8 qf[2];
#pragma unroll
  for (int c = 0; c < 2; ++c)
    qf[c] = *reinterpret_cast<const short8*>(&Qm[base + (size_t)(qw0 + r16) * 64 + c * 32 + g * 8]);

  f32x4 zero = {0.f, 0.f, 0.f, 0.f};
  f32x4 o[4];
#pragma unroll
  for (int ng = 0; ng < 4; ++ng) o[ng] = zero;
  float mrow[4], lrow[4];
#pragma unroll
  for (int j = 0; j < 4; ++j) { mrow[j] = -1e30f; lrow[j] = 0.f; }

  int ntw = ((qw0 + 15) >> 5) + 1; // per-wave tile count (no dead iterations)
  for (int kt = 0; kt < ntw; ++kt) {
    int key0 = kt << 5;
    // QK^T
    short8 kf0[2], kf1[2];
#pragma unroll
    for (int c = 0; c < 2; ++c) {
      kf0[c] = *reinterpret_cast<const short8*>(&Km[base + (size_t)(key0 + r16) * 64 + c * 32 + g * 8]);
      kf1[c] = *reinterpret_cast<const short8*>(&Km[base + (size_t)(key0 + 16 + r16) * 64 + c * 32 + g * 8]);
    }
    f32x4 s0 = zero, s1 = zero;
    s0 = __builtin_amdgcn_mfma_f32_16x16x32_bf16(qf[0], kf0[0], s0, 0, 0, 0);
    s0 = __builtin_amdgcn_mfma_f32_16x16x32_bf16(qf[1], kf0[1], s0, 0, 0, 0);
    s1 = __builtin_amdgcn_mfma_f32_16x16x32_bf16(qf[0], kf1[0], s1, 0, 0, 0);
    s1 = __builtin_amdgcn_mfma_f32_16x16x32_bf16(qf[1], kf1[1], s1, 0, 0, 0);

    float p0[4], p1[4], al[4];
#pragma unroll
    for (int j = 0; j < 4; ++j) {
      int row = qw0 + g * 4 + j;
      float v0 = s0[j] * 0.125f;
      if (key0 + r16 > row) v0 = -1e30f;
      float v1 = s1[j] * 0.125f;
      if (key0 + 16 + r16 > row) v1 = -1e30f;
      float vm = fmaxf(v0, v1);
#pragma unroll
      for (int off = 1; off < 16; off <<= 1) vm = fmaxf(vm, __shfl_xor(vm, off));
      float mn = fmaxf(mrow[j], vm);
      float a = __expf(mrow[j] - mn);
      p0[j] = __expf(v0 - mn);
      p1[j] = __expf(v1 - mn);
      float rs = p0[j] + p1[j];
#pragma unroll
      for (int off = 1; off < 16; off <<= 1) rs += __shfl_xor(rs, off);
      lrow[j] = lrow[j] * a + rs;
      mrow[j] = mn;
      al[j] = a;
    }
#pragma unroll
    for (int ng = 0; ng < 4; ++ng)
#pragma unroll
      for (int j = 0; j < 4; ++j) o[ng][j] *= al[j];
    // P tile through per-wave LDS (C-layout -> A-fragment re-layout)
#pragma unroll
    for (int j = 0; j < 4; ++j) {
      P[w][g * 4 + j][r16] = bf16_of(p0[j]);
      P[w][g * 4 + j][16 + r16] = bf16_of(p1[j]);
    }
    short8 pf = *reinterpret_cast<const short8*>(&P[w][r16][g * 8]);
#pragma unroll
    for (int ng = 0; ng < 4; ++ng) {
      short8 vf = *reinterpret_cast<const short8*>(
          &Vt[vbase + (size_t)(ng * 16 + r16) * TT + key0 + g * 8]);
      o[ng] = __builtin_amdgcn_mfma_f32_16x16x32_bf16(pf, vf, o[ng], 0, 0, 0);
    }
  }

  int b = bh >> 4, h = bh & 15;
#pragma unroll
  for (int ng = 0; ng < 4; ++ng)
#pragma unroll
    for (int j = 0; j < 4; ++j) {
      int t = qw0 + g * 4 + j;
      float val = o[ng][j] / lrow[j];
      Y[((size_t)(b * TT + t) * CCH) + h * 64 + ng * 16 + r16] = bf16_of(val);
    }
}

// ---------------- host ----------------
extern "C" void kernel_launch(void* const* d_in, const int* in_sizes, int n_in,
                              void* d_out, int out_size, void* d_ws, size_t ws_size,
                              hipStream_t stream) {
  const float* x      = (const float*)d_in[0];
  const float* w_attn = (const float*)d_in[1];
  const float* b_attn = (const float*)d_in[2];
  const float* w_proj = (const float*)d_in[3];
  const float* b_proj = (const float*)d_in[4];
  float* out = (float*)d_out;

  char* ws = (char*)d_ws;
  unsigned short* xb  = (unsigned short*)(ws + 0);          // 8192x1024 bf16; reused as Y
  unsigned short* wta = (unsigned short*)(ws + 16777216);   // 3072x1024 bf16
  unsigned short* wtp = (unsigned short*)(ws + 23068672);   // 1024x1024 bf16
  unsigned short* qb  = (unsigned short*)(ws + 25165824);   // q,k: [64][2048][64]; vt: [64][64][2048]
  unsigned short* yb  = xb;

  cast_f32_bf16<<<(MROWS * CCH) / 1024, 256, 0, stream>>>(x, xb, MROWS * CCH);
  transpose_cast<<<(CCH * 3 * CCH + 255) / 256, 256, 0, stream>>>(w_attn, wta, CCH, 3 * CCH);
  transpose_cast<<<(CCH * CCH + 255) / 256, 256, 0, stream>>>(w_proj, wtp, CCH, CCH);

  {
    dim3 grid(3 * CCH / 128, MROWS / 128);
    gemm_bt<1><<<grid, 256, 0, stream>>>(xb, wta, b_attn, nullptr, qb, MROWS, 3 * CCH, CCH);
  }
  {
    dim3 grid(TT / 64, BB * NHH);
    attn_kernel<<<grid, 256, 0, stream>>>(qb, qb + (size_t)QKV_ELEMS, qb + 2 * (size_t)QKV_ELEMS, yb);
  }
  {
    dim3 grid(CCH / 128, MROWS / 128);
    gemm_bt<0><<<grid, 256, 0, stream>>>(yb, wtp, b_proj, out, nullptr, MROWS, CCH, CCH);
  }
}

// Round 3
// 601.422 us; speedup vs baseline: 1.0016x; 1.0016x over previous
//
#include <hip/hip_runtime.h>
#include <hip/hip_bf16.h>

// Problem constants
#define BB 4
#define TT 2048
#define CCH 1024
#define NHH 16
#define HSS 64
#define MROWS (BB * TT)            // 8192
#define QKV_ELEMS (64 * 2048 * 64) // per-tensor elems = 8388608

typedef __attribute__((ext_vector_type(8))) short short8;
typedef __attribute__((ext_vector_type(4))) float f32x4;

static __device__ __forceinline__ unsigned short bf16_of(float f) {
  union { float f; unsigned u; } v; v.f = f;
  unsigned u = v.u;
  return (unsigned short)((u + 0x7FFFu + ((u >> 16) & 1u)) >> 16);
}

// ---------------- cast kernels ----------------
__global__ __launch_bounds__(256) void cast_f32_bf16(const float* __restrict__ in,
                                                     unsigned short* __restrict__ out, int n) {
  int i = (blockIdx.x * 256 + threadIdx.x) * 4;
  if (i < n) {
    float4 f = *reinterpret_cast<const float4*>(in + i);
    ushort4 o;
    o.x = bf16_of(f.x); o.y = bf16_of(f.y); o.z = bf16_of(f.z); o.w = bf16_of(f.w);
    *reinterpret_cast<ushort4*>(out + i) = o;
  }
}

// in: [K][N] f32 row-major -> out: [N][K] bf16 row-major
__global__ __launch_bounds__(256) void transpose_cast(const float* __restrict__ in,
                                                      unsigned short* __restrict__ out,
                                                      int K, int N) {
  int idx = blockIdx.x * 256 + threadIdx.x;
  if (idx < K * N) {
    int k = idx / N;
    int n = idx - k * N;
    out[(size_t)n * K + k] = bf16_of(in[idx]);
  }
}

// ---------------- GEMM: C = A[M,K] @ Bt[N,K]^T + bias ----------------
// MODE 0: write fp32 out[M,N]
// MODE 1: QKV epilogue -> bf16 q (pre-scaled by 1/8) / k in [B*NH][T][HS];
//         v transposed -> [B*NH][HS][T]
template <int MODE>
__global__ __launch_bounds__(256) void gemm_bt(const unsigned short* __restrict__ A,
                                               const unsigned short* __restrict__ Bt,
                                               const float* __restrict__ bias,
                                               float* __restrict__ outF,
                                               unsigned short* __restrict__ outQKV,
                                               int M, int N, int K) {
  __shared__ unsigned short As[128 * 32];
  __shared__ unsigned short Bs[128 * 32];
  int tid = threadIdx.x;
  int w = tid >> 6, lane = tid & 63;
  int g = lane >> 4, r16 = lane & 15;
  int wr = w >> 1, wc = w & 1;
  int m0 = blockIdx.y * 128, n0 = blockIdx.x * 128;
  int lrow = lane >> 2;           // 0..15 row within 16-row staging group
  int lcol = (lane & 3) * 8;      // ushort offset (16B chunks)

  f32x4 zero = {0.f, 0.f, 0.f, 0.f};
  f32x4 acc[4][4];
#pragma unroll
  for (int i = 0; i < 4; ++i)
#pragma unroll
    for (int n = 0; n < 4; ++n) acc[i][n] = zero;

  for (int kt = 0; kt < K; kt += 32) {
#pragma unroll
    for (int c = 0; c < 2; ++c) {
      int rg = w * 32 + c * 16;   // wave-uniform row-group base
      __builtin_amdgcn_global_load_lds(
          (const __attribute__((address_space(1))) void*)(&A[(size_t)(m0 + rg + lrow) * K + kt + lcol]),
          (__attribute__((address_space(3))) void*)(&As[rg * 32]), 16, 0, 0);
      __builtin_amdgcn_global_load_lds(
          (const __attribute__((address_space(1))) void*)(&Bt[(size_t)(n0 + rg + lrow) * K + kt + lcol]),
          (__attribute__((address_space(3))) void*)(&Bs[rg * 32]), 16, 0, 0);
    }
    __syncthreads();
    short8 af[4], bfr[4];
#pragma unroll
    for (int i = 0; i < 4; ++i)
      af[i] = *reinterpret_cast<const short8*>(&As[(wr * 64 + i * 16 + r16) * 32 + g * 8]);
#pragma unroll
    for (int i = 0; i < 4; ++i)
      bfr[i] = *reinterpret_cast<const short8*>(&Bs[(wc * 64 + i * 16 + r16) * 32 + g * 8]);
#pragma unroll
    for (int i = 0; i < 4; ++i)
#pragma unroll
      for (int n = 0; n < 4; ++n)
        acc[i][n] = __builtin_amdgcn_mfma_f32_16x16x32_bf16(af[i], bfr[n], acc[i][n], 0, 0, 0);
    __syncthreads();
  }

#pragma unroll
  for (int i = 0; i < 4; ++i)
#pragma unroll
    for (int n = 0; n < 4; ++n)
#pragma unroll
      for (int j = 0; j < 4; ++j) {
        int row = m0 + wr * 64 + i * 16 + g * 4 + j;
        int col = n0 + wc * 64 + n * 16 + r16;
        float val = acc[i][n][j] + bias[col];
        if (MODE == 0) {
          outF[(size_t)row * N + col] = val;
        } else {
          int which = col >> 10, c = col & 1023;
          int h = c >> 6, d = c & 63;
          int b = row >> 11, t = row & 2047;
          if (which == 2) {
            // V transposed: [bh][d][t]
            outQKV[2 * (size_t)QKV_ELEMS +
                   (((size_t)(b * 16 + h) * 64 + d) * 2048 + t)] = bf16_of(val);
          } else {
            if (which == 0) val *= 0.125f;   // fold 1/sqrt(HS) into Q
            outQKV[(size_t)which * QKV_ELEMS +
                   (((size_t)(b * 16 + h) * 2048 + t) * 64 + d)] = bf16_of(val);
          }
        }
      }
}

// ---------------- causal flash attention (prefetched, balanced) ----------------
// Q (pre-scaled),K: [B*NH][T][HS] bf16.  Vt: [B*NH][HS][T] bf16.  Y: [B][T][C] bf16.
__global__ __launch_bounds__(256) void attn_kernel(const unsigned short* __restrict__ Qm,
                                                   const unsigned short* __restrict__ Km,
                                                   const unsigned short* __restrict__ Vt,
                                                   unsigned short* __restrict__ Y) {
  __shared__ unsigned short P[4][16][32]; // per-wave private P tile

  int tid = threadIdx.x;
  int w = tid >> 6, lane = tid & 63;
  int g = lane >> 4, r16 = lane & 15;
  int bh = blockIdx.y;                         // 0..63
  int qblk = (int)(gridDim.x - 1 - blockIdx.x); // heavy-first (LPT balance)
  int qw0 = qblk * 64 + w * 16;
  const size_t base = (size_t)bh * TT * HSS;   // Q,K: [t][d]
  const size_t vbase = (size_t)bh * HSS * TT;  // Vt: [d][t]

  short8 qf[2];
#pragma unroll
  for (int c = 0; c < 2; ++c)
    qf[c] = *reinterpret_cast<const short8*>(&Qm[base + (size_t)(qw0 + r16) * 64 + c * 32 + g * 8]);

  f32x4 zero = {0.f, 0.f, 0.f, 0.f};
  f32x4 o[4];
#pragma unroll
  for (int ng = 0; ng < 4; ++ng) o[ng] = zero;
  float mrow[4], lrow[4];
#pragma unroll
  for (int j = 0; j < 4; ++j) { mrow[j] = -1e30f; lrow[j] = 0.f; }

  int ntw = ((qw0 + 15) >> 5) + 1; // per-wave tile count

  // prologue: K fragments for tile 0
  short8 ka[2], kb[2];
#pragma unroll
  for (int c = 0; c < 2; ++c) {
    ka[c] = *reinterpret_cast<const short8*>(&Km[base + (size_t)(r16) * 64 + c * 32 + g * 8]);
    kb[c] = *reinterpret_cast<const short8*>(&Km[base + (size_t)(16 + r16) * 64 + c * 32 + g * 8]);
  }

  for (int kt = 0; kt < ntw; ++kt) {
    int key0 = kt << 5;

    // issue V loads for CURRENT tile first (latency hidden under QK^T+softmax)
    short8 vf[4];
#pragma unroll
    for (int ng = 0; ng < 4; ++ng)
      vf[ng] = *reinterpret_cast<const short8*>(
          &Vt[vbase + (size_t)(ng * 16 + r16) * TT + key0 + g * 8]);

    // prefetch K for NEXT tile (clamped on last iteration; result discarded)
    int keyn = (kt + 1 < ntw) ? (key0 + 32) : 0;
    short8 kan[2], kbn[2];
#pragma unroll
    for (int c = 0; c < 2; ++c) {
      kan[c] = *reinterpret_cast<const short8*>(&Km[base + (size_t)(keyn + r16) * 64 + c * 32 + g * 8]);
      kbn[c] = *reinterpret_cast<const short8*>(&Km[base + (size_t)(keyn + 16 + r16) * 64 + c * 32 + g * 8]);
    }

    // QK^T (Q pre-scaled by 1/8)
    f32x4 s0 = zero, s1 = zero;
    s0 = __builtin_amdgcn_mfma_f32_16x16x32_bf16(qf[0], ka[0], s0, 0, 0, 0);
    s0 = __builtin_amdgcn_mfma_f32_16x16x32_bf16(qf[1], ka[1], s0, 0, 0, 0);
    s1 = __builtin_amdgcn_mfma_f32_16x16x32_bf16(qf[0], kb[0], s1, 0, 0, 0);
    s1 = __builtin_amdgcn_mfma_f32_16x16x32_bf16(qf[1], kb[1], s1, 0, 0, 0);

    float p0[4], p1[4], al[4];
#pragma unroll
    for (int j = 0; j < 4; ++j) {
      int row = qw0 + g * 4 + j;
      float v0 = s0[j];
      if (key0 + r16 > row) v0 = -1e30f;
      float v1 = s1[j];
      if (key0 + 16 + r16 > row) v1 = -1e30f;
      float vm = fmaxf(v0, v1);
#pragma unroll
      for (int off = 1; off < 16; off <<= 1) vm = fmaxf(vm, __shfl_xor(vm, off));
      float mn = fmaxf(mrow[j], vm);
      float a = __expf(mrow[j] - mn);
      p0[j] = __expf(v0 - mn);
      p1[j] = __expf(v1 - mn);
      float rs = p0[j] + p1[j];
#pragma unroll
      for (int off = 1; off < 16; off <<= 1) rs += __shfl_xor(rs, off);
      lrow[j] = lrow[j] * a + rs;
      mrow[j] = mn;
      al[j] = a;
    }
#pragma unroll
    for (int ng = 0; ng < 4; ++ng)
#pragma unroll
      for (int j = 0; j < 4; ++j) o[ng][j] *= al[j];

    // P tile through per-wave LDS (C-layout -> A-fragment re-layout)
#pragma unroll
    for (int j = 0; j < 4; ++j) {
      P[w][g * 4 + j][r16] = bf16_of(p0[j]);
      P[w][g * 4 + j][16 + r16] = bf16_of(p1[j]);
    }
    short8 pf = *reinterpret_cast<const short8*>(&P[w][r16][g * 8]);
#pragma unroll
    for (int ng = 0; ng < 4; ++ng)
      o[ng] = __builtin_amdgcn_mfma_f32_16x16x32_bf16(pf, vf[ng], o[ng], 0, 0, 0);

#pragma unroll
    for (int c = 0; c < 2; ++c) { ka[c] = kan[c]; kb[c] = kbn[c]; }
  }

  int b = bh >> 4, h = bh & 15;
#pragma unroll
  for (int ng = 0; ng < 4; ++ng)
#pragma unroll
    for (int j = 0; j < 4; ++j) {
      int t = qw0 + g * 4 + j;
      float val = o[ng][j] / lrow[j];
      Y[((size_t)(b * TT + t) * CCH) + h * 64 + ng * 16 + r16] = bf16_of(val);
    }
}

// ---------------- host ----------------
extern "C" void kernel_launch(void* const* d_in, const int* in_sizes, int n_in,
                              void* d_out, int out_size, void* d_ws, size_t ws_size,
                              hipStream_t stream) {
  const float* x      = (const float*)d_in[0];
  const float* w_attn = (const float*)d_in[1];
  const float* b_attn = (const float*)d_in[2];
  const float* w_proj = (const float*)d_in[3];
  const float* b_proj = (const float*)d_in[4];
  float* out = (float*)d_out;

  char* ws = (char*)d_ws;
  unsigned short* xb  = (unsigned short*)(ws + 0);          // 8192x1024 bf16; reused as Y
  unsigned short* wta = (unsigned short*)(ws + 16777216);   // 3072x1024 bf16
  unsigned short* wtp = (unsigned short*)(ws + 23068672);   // 1024x1024 bf16
  unsigned short* qb  = (unsigned short*)(ws + 25165824);   // q,k: [64][2048][64]; vt: [64][64][2048]
  unsigned short* yb  = xb;

  cast_f32_bf16<<<(MROWS * CCH) / 1024, 256, 0, stream>>>(x, xb, MROWS * CCH);
  transpose_cast<<<(CCH * 3 * CCH + 255) / 256, 256, 0, stream>>>(w_attn, wta, CCH, 3 * CCH);
  transpose_cast<<<(CCH * CCH + 255) / 256, 256, 0, stream>>>(w_proj, wtp, CCH, CCH);

  {
    dim3 grid(3 * CCH / 128, MROWS / 128);
    gemm_bt<1><<<grid, 256, 0, stream>>>(xb, wta, b_attn, nullptr, qb, MROWS, 3 * CCH, CCH);
  }
  {
    dim3 grid(TT / 64, BB * NHH);
    attn_kernel<<<grid, 256, 0, stream>>>(qb, qb + (size_t)QKV_ELEMS, qb + 2 * (size_t)QKV_ELEMS, yb);
  }
  {
    dim3 grid(CCH / 128, MROWS / 128);
    gemm_bt<0><<<grid, 256, 0, stream>>>(yb, wtp, b_proj, out, nullptr, MROWS, CCH, CCH);
  }
}

// Round 6
// 596.033 us; speedup vs baseline: 1.0106x; 1.0090x over previous
//
#include <hip/hip_runtime.h>
#include <hip/hip_bf16.h>

// Problem constants
#define BB 4
#define TT 2048
#define CCH 1024
#define NHH 16
#define HSS 64
#define MROWS (BB * TT)            // 8192
#define QKV_ELEMS (64 * 2048 * 64) // per-tensor elems = 8388608

typedef __attribute__((ext_vector_type(8))) short short8;
typedef __attribute__((ext_vector_type(4))) float f32x4;

#define CVTPK(d, a, b) asm("v_cvt_pk_bf16_f32 %0, %1, %2" : "=v"(d) : "v"(a), "v"(b))

static __device__ __forceinline__ unsigned short bf16_of(float f) {
  union { float f; unsigned u; } v; v.f = f;
  unsigned u = v.u;
  return (unsigned short)((u + 0x7FFFu + ((u >> 16) & 1u)) >> 16);
}

// ---------------- cast kernels ----------------
__global__ __launch_bounds__(256) void cast_f32_bf16(const float* __restrict__ in,
                                                     unsigned short* __restrict__ out, int n) {
  int i = (blockIdx.x * 256 + threadIdx.x) * 4;
  if (i < n) {
    float4 f = *reinterpret_cast<const float4*>(in + i);
    ushort4 o;
    o.x = bf16_of(f.x); o.y = bf16_of(f.y); o.z = bf16_of(f.z); o.w = bf16_of(f.w);
    *reinterpret_cast<ushort4*>(out + i) = o;
  }
}

// in: [K][N] f32 row-major -> out: [N][K] bf16 row-major
__global__ __launch_bounds__(256) void transpose_cast(const float* __restrict__ in,
                                                      unsigned short* __restrict__ out,
                                                      int K, int N) {
  int idx = blockIdx.x * 256 + threadIdx.x;
  if (idx < K * N) {
    int k = idx / N;
    int n = idx - k * N;
    out[(size_t)n * K + k] = bf16_of(in[idx]);
  }
}

// ---------------- GEMM: C = A[M,K] @ Bt[N,K]^T + bias (verified R1-R3) ----------------
template <int MODE>
__global__ __launch_bounds__(256) void gemm_bt(const unsigned short* __restrict__ A,
                                               const unsigned short* __restrict__ Bt,
                                               const float* __restrict__ bias,
                                               float* __restrict__ outF,
                                               unsigned short* __restrict__ outQKV,
                                               int M, int N, int K) {
  __shared__ unsigned short As[128 * 32];
  __shared__ unsigned short Bs[128 * 32];
  int tid = threadIdx.x;
  int w = tid >> 6, lane = tid & 63;
  int g = lane >> 4, r16 = lane & 15;
  int wr = w >> 1, wc = w & 1;
  int m0 = blockIdx.y * 128, n0 = blockIdx.x * 128;
  int lrow = lane >> 2;
  int lcol = (lane & 3) * 8;

  f32x4 zero = {0.f, 0.f, 0.f, 0.f};
  f32x4 acc[4][4];
#pragma unroll
  for (int i = 0; i < 4; ++i)
#pragma unroll
    for (int n = 0; n < 4; ++n) acc[i][n] = zero;

  for (int kt = 0; kt < K; kt += 32) {
#pragma unroll
    for (int c = 0; c < 2; ++c) {
      int rg = w * 32 + c * 16;
      __builtin_amdgcn_global_load_lds(
          (const __attribute__((address_space(1))) void*)(&A[(size_t)(m0 + rg + lrow) * K + kt + lcol]),
          (__attribute__((address_space(3))) void*)(&As[rg * 32]), 16, 0, 0);
      __builtin_amdgcn_global_load_lds(
          (const __attribute__((address_space(1))) void*)(&Bt[(size_t)(n0 + rg + lrow) * K + kt + lcol]),
          (__attribute__((address_space(3))) void*)(&Bs[rg * 32]), 16, 0, 0);
    }
    __syncthreads();
    short8 af[4], bfr[4];
#pragma unroll
    for (int i = 0; i < 4; ++i)
      af[i] = *reinterpret_cast<const short8*>(&As[(wr * 64 + i * 16 + r16) * 32 + g * 8]);
#pragma unroll
    for (int i = 0; i < 4; ++i)
      bfr[i] = *reinterpret_cast<const short8*>(&Bs[(wc * 64 + i * 16 + r16) * 32 + g * 8]);
#pragma unroll
    for (int i = 0; i < 4; ++i)
#pragma unroll
      for (int n = 0; n < 4; ++n)
        acc[i][n] = __builtin_amdgcn_mfma_f32_16x16x32_bf16(af[i], bfr[n], acc[i][n], 0, 0, 0);
    __syncthreads();
  }

#pragma unroll
  for (int i = 0; i < 4; ++i)
#pragma unroll
    for (int n = 0; n < 4; ++n)
#pragma unroll
      for (int j = 0; j < 4; ++j) {
        int row = m0 + wr * 64 + i * 16 + g * 4 + j;
        int col = n0 + wc * 64 + n * 16 + r16;
        float val = acc[i][n][j] + bias[col];
        if (MODE == 0) {
          outF[(size_t)row * N + col] = val;
        } else {
          int which = col >> 10, c = col & 1023;
          int h = c >> 6, d = c & 63;
          int b = row >> 11, t = row & 2047;
          if (which == 2) {
            outQKV[2 * (size_t)QKV_ELEMS +
                   (((size_t)(b * 16 + h) * 64 + d) * 2048 + t)] = bf16_of(val);
          } else {
            if (which == 0) val *= 0.125f;   // fold 1/sqrt(HS) into Q (exact pow2)
            outQKV[(size_t)which * QKV_ELEMS +
                   (((size_t)(b * 16 + h) * 2048 + t) * 64 + d)] = bf16_of(val);
          }
        }
      }
}

// ---------------- causal flash attention: swapped QK^T on 16x16x32 ----------------
// S = mfma(K_frag, Q_frag): lane owns q-row (l&15), keys (l>>4)*4+reg per 16-key half.
// All fragment layouts session-verified (R1-R3). No LDS arrays, no barriers.
// MODE 0: full 32-key tile. MODE 1: kb0 full, kb1 diagonal. MODE 2: 16-key diagonal only.
template <int MODE>
static __device__ __forceinline__ void attn_tile16(int key0, int r16, int g4,
                                                   const unsigned short* __restrict__ Kp,
                                                   const unsigned short* __restrict__ Vp,
                                                   const short8 qf[2],
                                                   f32x4 o[4], float& m, float& lsum) {
  f32x4 zero = {0.f, 0.f, 0.f, 0.f};
  short8 z8 = {0, 0, 0, 0, 0, 0, 0, 0};

  // K A-fragments: row = key0 + kb*16 + r16, k(d) = c*32 + g4*8 + j
  short8 kf0[2], kf1[2];
#pragma unroll
  for (int c = 0; c < 2; ++c)
    kf0[c] = *reinterpret_cast<const short8*>(&Kp[(size_t)(key0 + r16) * 64 + c * 32 + g4 * 8]);
  if (MODE != 2) {
#pragma unroll
    for (int c = 0; c < 2; ++c)
      kf1[c] = *reinterpret_cast<const short8*>(&Kp[(size_t)(key0 + 16 + r16) * 64 + c * 32 + g4 * 8]);
  }

  // V^T A-fragments: row(d) = dblk*16 + r16, k(key) = g4*8 + j
  short8 vf[4];
#pragma unroll
  for (int dblk = 0; dblk < 4; ++dblk) {
    if (MODE == 2)
      vf[dblk] = (g4 < 2)
          ? *reinterpret_cast<const short8*>(&Vp[(size_t)(dblk * 16 + r16) * TT + key0 + g4 * 8])
          : z8;
    else
      vf[dblk] = *reinterpret_cast<const short8*>(&Vp[(size_t)(dblk * 16 + r16) * TT + key0 + g4 * 8]);
  }

  // S halves
  f32x4 s0 = zero, s1 = zero;
  s0 = __builtin_amdgcn_mfma_f32_16x16x32_bf16(kf0[0], qf[0], s0, 0, 0, 0);
  s0 = __builtin_amdgcn_mfma_f32_16x16x32_bf16(kf0[1], qf[1], s0, 0, 0, 0);
  if (MODE != 2) {
    s1 = __builtin_amdgcn_mfma_f32_16x16x32_bf16(kf1[0], qf[0], s1, 0, 0, 0);
    s1 = __builtin_amdgcn_mfma_f32_16x16x32_bf16(kf1[1], qf[1], s1, 0, 0, 0);
  }

  // causal mask on the diagonal half (key offset g4*4+r vs q-row offset r16)
  if (MODE == 2) {
#pragma unroll
    for (int r = 0; r < 4; ++r)
      if (g4 * 4 + r > r16) s0[r] = -1e30f;
  }
  if (MODE == 1) {
#pragma unroll
    for (int r = 0; r < 4; ++r)
      if (g4 * 4 + r > r16) s1[r] = -1e30f;
  }

  // softmax (cross-lane reduce over g4 groups: xor 16, xor 32)
  float om = fmaxf(fmaxf(s0[0], s0[1]), fmaxf(s0[2], s0[3]));
  if (MODE != 2)
    om = fmaxf(om, fmaxf(fmaxf(s1[0], s1[1]), fmaxf(s1[2], s1[3])));
  om = fmaxf(om, __shfl_xor(om, 16));
  om = fmaxf(om, __shfl_xor(om, 32));
  float mn = fmaxf(m, om);
  float alpha = __expf(m - mn);
  m = mn;

  float p0[4], p1[4];
#pragma unroll
  for (int r = 0; r < 4; ++r) {
    p0[r] = __expf(s0[r] - mn);
    p1[r] = (MODE == 2) ? 0.f : __expf(s1[r] - mn);
  }
  float rs = (p0[0] + p0[1]) + (p0[2] + p0[3]);
  if (MODE != 2) rs += (p1[0] + p1[1]) + (p1[2] + p1[3]);
  rs += __shfl_xor(rs, 16);
  rs += __shfl_xor(rs, 32);
  lsum = lsum * alpha + rs;
#pragma unroll
  for (int dblk = 0; dblk < 4; ++dblk)
#pragma unroll
    for (int r = 0; r < 4; ++r) o[dblk][r] *= alpha;

  // pack own P (keys kb*16 + g4*4 + {0..3}) into 2 words per half
  int w00, w01, w10, w11;
  CVTPK(w00, p0[0], p0[1]); CVTPK(w01, p0[2], p0[3]);
  CVTPK(w10, p1[0], p1[1]); CVTPK(w11, p1[2], p1[3]);

  // redistribute to PV B-fragment: pf[j] = P[key0 + g4*8 + j][qrow]
  // pf.w[W] = w[g4>>1][W&1] from src lane r16 + 32*(g4&1) + 16*(W>>1)
  int srcA = r16 + 32 * (g4 & 1);
  int srcB = srcA + 16;
  int a0 = __shfl(w00, srcA, 64), b0 = __shfl(w10, srcA, 64);
  int a1 = __shfl(w01, srcA, 64), b1 = __shfl(w11, srcA, 64);
  int a2 = __shfl(w00, srcB, 64), b2 = __shfl(w10, srcB, 64);
  int a3 = __shfl(w01, srcB, 64), b3 = __shfl(w11, srcB, 64);
  bool hi = (g4 >> 1);
  union { int w[4]; short8 s8; } pf;
  pf.w[0] = hi ? b0 : a0;
  pf.w[1] = hi ? b1 : a1;
  pf.w[2] = hi ? b2 : a2;
  pf.w[3] = hi ? b3 : a3;

  // O^T[d][qrow] += V^T · P   (4 d-blocks of 16)
#pragma unroll
  for (int dblk = 0; dblk < 4; ++dblk)
    o[dblk] = __builtin_amdgcn_mfma_f32_16x16x32_bf16(vf[dblk], pf.s8, o[dblk], 0, 0, 0);
}

__global__ __launch_bounds__(256) void attn_kernel(const unsigned short* __restrict__ Qm,
                                                   const unsigned short* __restrict__ Km,
                                                   const unsigned short* __restrict__ Vt,
                                                   unsigned short* __restrict__ Y) {
  int tid = threadIdx.x;
  int w = tid >> 6, lane = tid & 63;
  int r16 = lane & 15, g4 = lane >> 4;
  int bh = blockIdx.y;
  int qb = (int)(gridDim.x - 1 - blockIdx.x);  // heavy-first
  int qw0 = qb * 64 + w * 16;                  // 16-row strip per wave
  const unsigned short* Qp = Qm + (size_t)bh * TT * HSS;
  const unsigned short* Kp = Km + (size_t)bh * TT * HSS;
  const unsigned short* Vp = Vt + (size_t)bh * HSS * TT;

  // Q B-fragments: col = qrow = qw0 + r16, k(d) = c*32 + g4*8 + j
  short8 qf[2];
#pragma unroll
  for (int c = 0; c < 2; ++c)
    qf[c] = *reinterpret_cast<const short8*>(&Qp[(size_t)(qw0 + r16) * 64 + c * 32 + g4 * 8]);

  f32x4 o[4];
#pragma unroll
  for (int dblk = 0; dblk < 4; ++dblk) o[dblk] = f32x4{0.f, 0.f, 0.f, 0.f};
  float m = -1e30f, lsum = 0.f;

  int nfull = qw0 >> 5;   // full 32-key tiles
  for (int kt = 0; kt < nfull; ++kt)
    attn_tile16<0>(kt << 5, r16, g4, Kp, Vp, qf, o, m, lsum);
  if (qw0 & 16)
    attn_tile16<1>(qw0 - 16, r16, g4, Kp, Vp, qf, o, m, lsum);
  else
    attn_tile16<2>(qw0, r16, g4, Kp, Vp, qf, o, m, lsum);

  // epilogue: lane holds O^T[d = dblk*16 + g4*4 + r][qrow = qw0 + r16]
  int b = bh >> 4, h = bh & 15;
  float inv = 1.0f / lsum;
  unsigned short* yrow = Y + ((size_t)(b * TT + qw0 + r16) * CCH) + h * 64;
#pragma unroll
  for (int dblk = 0; dblk < 4; ++dblk) {
    float v0 = o[dblk][0] * inv, v1 = o[dblk][1] * inv;
    float v2 = o[dblk][2] * inv, v3 = o[dblk][3] * inv;
    int wa, wb;
    CVTPK(wa, v0, v1);
    CVTPK(wb, v2, v3);
    int2 pk; pk.x = wa; pk.y = wb;
    *reinterpret_cast<int2*>(&yrow[dblk * 16 + g4 * 4]) = pk;
  }
}

// ---------------- host ----------------
extern "C" void kernel_launch(void* const* d_in, const int* in_sizes, int n_in,
                              void* d_out, int out_size, void* d_ws, size_t ws_size,
                              hipStream_t stream) {
  const float* x      = (const float*)d_in[0];
  const float* w_attn = (const float*)d_in[1];
  const float* b_attn = (const float*)d_in[2];
  const float* w_proj = (const float*)d_in[3];
  const float* b_proj = (const float*)d_in[4];
  float* out = (float*)d_out;

  char* ws = (char*)d_ws;
  unsigned short* xb  = (unsigned short*)(ws + 0);          // 8192x1024 bf16; reused as Y
  unsigned short* wta = (unsigned short*)(ws + 16777216);   // 3072x1024 bf16
  unsigned short* wtp = (unsigned short*)(ws + 23068672);   // 1024x1024 bf16
  unsigned short* qb  = (unsigned short*)(ws + 25165824);   // q,k: [64][2048][64]; vt: [64][64][2048]
  unsigned short* yb  = xb;

  cast_f32_bf16<<<(MROWS * CCH) / 1024, 256, 0, stream>>>(x, xb, MROWS * CCH);
  transpose_cast<<<(CCH * 3 * CCH + 255) / 256, 256, 0, stream>>>(w_attn, wta, CCH, 3 * CCH);
  transpose_cast<<<(CCH * CCH + 255) / 256, 256, 0, stream>>>(w_proj, wtp, CCH, CCH);

  {
    dim3 grid(3 * CCH / 128, MROWS / 128);
    gemm_bt<1><<<grid, 256, 0, stream>>>(xb, wta, b_attn, nullptr, qb, MROWS, 3 * CCH, CCH);
  }
  {
    dim3 grid(TT / 64, BB * NHH);
    attn_kernel<<<grid, 256, 0, stream>>>(qb, qb + (size_t)QKV_ELEMS, qb + 2 * (size_t)QKV_ELEMS, yb);
  }
  {
    dim3 grid(CCH / 128, MROWS / 128);
    gemm_bt<0><<<grid, 256, 0, stream>>>(yb, wtp, b_proj, out, nullptr, MROWS, CCH, CCH);
  }
}

// Round 7
// 386.827 us; speedup vs baseline: 1.5572x; 1.5408x over previous
//
#include <hip/hip_runtime.h>
#include <hip/hip_bf16.h>

// Problem constants
#define BB 4
#define TT 2048
#define CCH 1024
#define NHH 16
#define HSS 64
#define MROWS (BB * TT)            // 8192
#define QKV_ELEMS (64 * 2048 * 64) // per-tensor elems = 8388608

typedef __attribute__((ext_vector_type(8))) short short8;
typedef __attribute__((ext_vector_type(4))) float f32x4;

#define CVTPK(d, a, b) asm("v_cvt_pk_bf16_f32 %0, %1, %2" : "=v"(d) : "v"(a), "v"(b))

static __device__ __forceinline__ unsigned short bf16_of(float f) {
  union { float f; unsigned u; } v; v.f = f;
  unsigned u = v.u;
  return (unsigned short)((u + 0x7FFFu + ((u >> 16) & 1u)) >> 16);
}

// ---------------- cast kernels ----------------
__global__ __launch_bounds__(256) void cast_f32_bf16(const float* __restrict__ in,
                                                     unsigned short* __restrict__ out, int n) {
  int i = (blockIdx.x * 256 + threadIdx.x) * 4;
  if (i < n) {
    float4 f = *reinterpret_cast<const float4*>(in + i);
    ushort4 o;
    o.x = bf16_of(f.x); o.y = bf16_of(f.y); o.z = bf16_of(f.z); o.w = bf16_of(f.w);
    *reinterpret_cast<ushort4*>(out + i) = o;
  }
}

// in: [K][N] f32 row-major -> out: [N][K] bf16 row-major
__global__ __launch_bounds__(256) void transpose_cast(const float* __restrict__ in,
                                                      unsigned short* __restrict__ out,
                                                      int K, int N) {
  int idx = blockIdx.x * 256 + threadIdx.x;
  if (idx < K * N) {
    int k = idx / N;
    int n = idx - k * N;
    out[(size_t)n * K + k] = bf16_of(in[idx]);
  }
}

// ---------------- GEMM: C = A[M,K] @ Bt[N,K]^T + bias (verified R1-R3) ----------------
template <int MODE>
__global__ __launch_bounds__(256) void gemm_bt(const unsigned short* __restrict__ A,
                                               const unsigned short* __restrict__ Bt,
                                               const float* __restrict__ bias,
                                               float* __restrict__ outF,
                                               unsigned short* __restrict__ outQKV,
                                               int M, int N, int K) {
  __shared__ unsigned short As[128 * 32];
  __shared__ unsigned short Bs[128 * 32];
  int tid = threadIdx.x;
  int w = tid >> 6, lane = tid & 63;
  int g = lane >> 4, r16 = lane & 15;
  int wr = w >> 1, wc = w & 1;
  int m0 = blockIdx.y * 128, n0 = blockIdx.x * 128;
  int lrow = lane >> 2;
  int lcol = (lane & 3) * 8;

  f32x4 zero = {0.f, 0.f, 0.f, 0.f};
  f32x4 acc[4][4];
#pragma unroll
  for (int i = 0; i < 4; ++i)
#pragma unroll
    for (int n = 0; n < 4; ++n) acc[i][n] = zero;

  for (int kt = 0; kt < K; kt += 32) {
#pragma unroll
    for (int c = 0; c < 2; ++c) {
      int rg = w * 32 + c * 16;
      __builtin_amdgcn_global_load_lds(
          (const __attribute__((address_space(1))) void*)(&A[(size_t)(m0 + rg + lrow) * K + kt + lcol]),
          (__attribute__((address_space(3))) void*)(&As[rg * 32]), 16, 0, 0);
      __builtin_amdgcn_global_load_lds(
          (const __attribute__((address_space(1))) void*)(&Bt[(size_t)(n0 + rg + lrow) * K + kt + lcol]),
          (__attribute__((address_space(3))) void*)(&Bs[rg * 32]), 16, 0, 0);
    }
    __syncthreads();
    short8 af[4], bfr[4];
#pragma unroll
    for (int i = 0; i < 4; ++i)
      af[i] = *reinterpret_cast<const short8*>(&As[(wr * 64 + i * 16 + r16) * 32 + g * 8]);
#pragma unroll
    for (int i = 0; i < 4; ++i)
      bfr[i] = *reinterpret_cast<const short8*>(&Bs[(wc * 64 + i * 16 + r16) * 32 + g * 8]);
#pragma unroll
    for (int i = 0; i < 4; ++i)
#pragma unroll
      for (int n = 0; n < 4; ++n)
        acc[i][n] = __builtin_amdgcn_mfma_f32_16x16x32_bf16(af[i], bfr[n], acc[i][n], 0, 0, 0);
    __syncthreads();
  }

#pragma unroll
  for (int i = 0; i < 4; ++i)
#pragma unroll
    for (int n = 0; n < 4; ++n)
#pragma unroll
      for (int j = 0; j < 4; ++j) {
        int row = m0 + wr * 64 + i * 16 + g * 4 + j;
        int col = n0 + wc * 64 + n * 16 + r16;
        float val = acc[i][n][j] + bias[col];
        if (MODE == 0) {
          outF[(size_t)row * N + col] = val;
        } else {
          int which = col >> 10, c = col & 1023;
          int h = c >> 6, d = c & 63;
          int b = row >> 11, t = row & 2047;
          if (which == 2) {
            outQKV[2 * (size_t)QKV_ELEMS +
                   (((size_t)(b * 16 + h) * 64 + d) * 2048 + t)] = bf16_of(val);
          } else {
            if (which == 0) val *= 0.125f;   // fold 1/sqrt(HS) into Q (exact pow2)
            outQKV[(size_t)which * QKV_ELEMS +
                   (((size_t)(b * 16 + h) * 2048 + t) * 64 + d)] = bf16_of(val);
          }
        }
      }
}

// ---------------- causal flash attention: swapped QK^T on 16x16x32 (R6-verified math) ----
// Register double-buffered tiles + balanced strip pairs {i, 127-i} per wave.
struct Frags { short8 kf0[2], kf1[2], vf[4]; };

template <int MODE>
static __device__ __forceinline__ void load_frags(Frags& f, int key0, int r16, int g4,
                                                  const unsigned short* __restrict__ Kp,
                                                  const unsigned short* __restrict__ Vp) {
  short8 z8 = {0, 0, 0, 0, 0, 0, 0, 0};
#pragma unroll
  for (int c = 0; c < 2; ++c)
    f.kf0[c] = *reinterpret_cast<const short8*>(&Kp[(size_t)(key0 + r16) * 64 + c * 32 + g4 * 8]);
  if (MODE != 2) {
#pragma unroll
    for (int c = 0; c < 2; ++c)
      f.kf1[c] = *reinterpret_cast<const short8*>(&Kp[(size_t)(key0 + 16 + r16) * 64 + c * 32 + g4 * 8]);
  }
#pragma unroll
  for (int dblk = 0; dblk < 4; ++dblk) {
    if (MODE == 2)
      f.vf[dblk] = (g4 < 2)
          ? *reinterpret_cast<const short8*>(&Vp[(size_t)(dblk * 16 + r16) * TT + key0 + g4 * 8])
          : z8;
    else
      f.vf[dblk] = *reinterpret_cast<const short8*>(&Vp[(size_t)(dblk * 16 + r16) * TT + key0 + g4 * 8]);
  }
}

template <int MODE>
static __device__ __forceinline__ void compute_tile(const Frags& f, int r16, int g4,
                                                    const short8 qf[2], f32x4 o[4],
                                                    float& m, float& lsum) {
  f32x4 zero = {0.f, 0.f, 0.f, 0.f};
  f32x4 s0 = zero, s1 = zero;
  __builtin_amdgcn_s_setprio(1);
  s0 = __builtin_amdgcn_mfma_f32_16x16x32_bf16(f.kf0[0], qf[0], s0, 0, 0, 0);
  s0 = __builtin_amdgcn_mfma_f32_16x16x32_bf16(f.kf0[1], qf[1], s0, 0, 0, 0);
  if (MODE != 2) {
    s1 = __builtin_amdgcn_mfma_f32_16x16x32_bf16(f.kf1[0], qf[0], s1, 0, 0, 0);
    s1 = __builtin_amdgcn_mfma_f32_16x16x32_bf16(f.kf1[1], qf[1], s1, 0, 0, 0);
  }
  __builtin_amdgcn_s_setprio(0);

  if (MODE == 2) {
#pragma unroll
    for (int r = 0; r < 4; ++r)
      if (g4 * 4 + r > r16) s0[r] = -1e30f;
  }
  if (MODE == 1) {
#pragma unroll
    for (int r = 0; r < 4; ++r)
      if (g4 * 4 + r > r16) s1[r] = -1e30f;
  }

  float om = fmaxf(fmaxf(s0[0], s0[1]), fmaxf(s0[2], s0[3]));
  if (MODE != 2)
    om = fmaxf(om, fmaxf(fmaxf(s1[0], s1[1]), fmaxf(s1[2], s1[3])));
  om = fmaxf(om, __shfl_xor(om, 16));
  om = fmaxf(om, __shfl_xor(om, 32));
  float mn = fmaxf(m, om);
  float alpha = __expf(m - mn);
  m = mn;

  float p0[4], p1[4];
#pragma unroll
  for (int r = 0; r < 4; ++r) {
    p0[r] = __expf(s0[r] - mn);
    p1[r] = (MODE == 2) ? 0.f : __expf(s1[r] - mn);
  }
  float rs = (p0[0] + p0[1]) + (p0[2] + p0[3]);
  if (MODE != 2) rs += (p1[0] + p1[1]) + (p1[2] + p1[3]);
  rs += __shfl_xor(rs, 16);
  rs += __shfl_xor(rs, 32);
  lsum = lsum * alpha + rs;
#pragma unroll
  for (int dblk = 0; dblk < 4; ++dblk)
#pragma unroll
    for (int r = 0; r < 4; ++r) o[dblk][r] *= alpha;

  int w00, w01, w10, w11;
  CVTPK(w00, p0[0], p0[1]); CVTPK(w01, p0[2], p0[3]);
  CVTPK(w10, p1[0], p1[1]); CVTPK(w11, p1[2], p1[3]);

  int srcA = r16 + 32 * (g4 & 1);
  int srcB = srcA + 16;
  int a0 = __shfl(w00, srcA, 64), b0 = __shfl(w10, srcA, 64);
  int a1 = __shfl(w01, srcA, 64), b1 = __shfl(w11, srcA, 64);
  int a2 = __shfl(w00, srcB, 64), b2 = __shfl(w10, srcB, 64);
  int a3 = __shfl(w01, srcB, 64), b3 = __shfl(w11, srcB, 64);
  bool hi = (g4 >> 1);
  union { int w[4]; short8 s8; } pf;
  pf.w[0] = hi ? b0 : a0;
  pf.w[1] = hi ? b1 : a1;
  pf.w[2] = hi ? b2 : a2;
  pf.w[3] = hi ? b3 : a3;

  __builtin_amdgcn_s_setprio(1);
#pragma unroll
  for (int dblk = 0; dblk < 4; ++dblk)
    o[dblk] = __builtin_amdgcn_mfma_f32_16x16x32_bf16(f.vf[dblk], pf.s8, o[dblk], 0, 0, 0);
  __builtin_amdgcn_s_setprio(0);
}

// process one 16-row q-strip (TAILMODE = 1 if qw0&16 else 2)
template <int TAILMODE>
static __device__ __forceinline__ void do_strip(int qw0, int r16, int g4,
                                                const unsigned short* __restrict__ Qp,
                                                const unsigned short* __restrict__ Kp,
                                                const unsigned short* __restrict__ Vp,
                                                unsigned short* __restrict__ Y,
                                                int b, int h) {
  short8 qf[2];
#pragma unroll
  for (int c = 0; c < 2; ++c)
    qf[c] = *reinterpret_cast<const short8*>(&Qp[(size_t)(qw0 + r16) * 64 + c * 32 + g4 * 8]);

  f32x4 o[4];
#pragma unroll
  for (int dblk = 0; dblk < 4; ++dblk) o[dblk] = f32x4{0.f, 0.f, 0.f, 0.f};
  float m = -1e30f, lsum = 0.f;

  int nfull = qw0 >> 5;
  Frags fA, fB;
  if (nfull > 0) {
    load_frags<0>(fA, 0, r16, g4, Kp, Vp);
    int t = 0;
    while (t + 1 < nfull) {
      load_frags<0>(fB, (t + 1) << 5, r16, g4, Kp, Vp);
      compute_tile<0>(fA, r16, g4, qf, o, m, lsum);
      if (t + 2 < nfull) load_frags<0>(fA, (t + 2) << 5, r16, g4, Kp, Vp);
      compute_tile<0>(fB, r16, g4, qf, o, m, lsum);
      t += 2;
    }
    if (t < nfull) compute_tile<0>(fA, r16, g4, qf, o, m, lsum);
  }
  load_frags<TAILMODE>(fA, nfull << 5, r16, g4, Kp, Vp);
  compute_tile<TAILMODE>(fA, r16, g4, qf, o, m, lsum);

  float inv = 1.0f / lsum;
  unsigned short* yrow = Y + ((size_t)(b * TT + qw0 + r16) * CCH) + h * 64;
#pragma unroll
  for (int dblk = 0; dblk < 4; ++dblk) {
    float v0 = o[dblk][0] * inv, v1 = o[dblk][1] * inv;
    float v2 = o[dblk][2] * inv, v3 = o[dblk][3] * inv;
    int wa, wb;
    CVTPK(wa, v0, v1);
    CVTPK(wb, v2, v3);
    int2 pk; pk.x = wa; pk.y = wb;
    *reinterpret_cast<int2*>(&yrow[dblk * 16 + g4 * 4]) = pk;
  }
}

__global__ __launch_bounds__(256, 4) void attn_kernel(const unsigned short* __restrict__ Qm,
                                                      const unsigned short* __restrict__ Km,
                                                      const unsigned short* __restrict__ Vt,
                                                      unsigned short* __restrict__ Y) {
  int tid = threadIdx.x;
  int w = tid >> 6, lane = tid & 63;
  int r16 = lane & 15, g4 = lane >> 4;
  int bh = blockIdx.y;
  int i = blockIdx.x * 4 + w;      // pair index 0..63
  const unsigned short* Qp = Qm + (size_t)bh * TT * HSS;
  const unsigned short* Kp = Km + (size_t)bh * TT * HSS;
  const unsigned short* Vp = Vt + (size_t)bh * HSS * TT;
  int b = bh >> 4, h = bh & 15;

  // strip pair {i, 127-i}: total tiles = 65 for every wave (perfect balance)
#pragma unroll
  for (int sidx = 0; sidx < 2; ++sidx) {
    int s = sidx ? (127 - i) : i;
    int qw0 = s * 16;
    if (qw0 & 16)
      do_strip<1>(qw0, r16, g4, Qp, Kp, Vp, Y, b, h);
    else
      do_strip<2>(qw0, r16, g4, Qp, Kp, Vp, Y, b, h);
  }
}

// ---------------- host ----------------
extern "C" void kernel_launch(void* const* d_in, const int* in_sizes, int n_in,
                              void* d_out, int out_size, void* d_ws, size_t ws_size,
                              hipStream_t stream) {
  const float* x      = (const float*)d_in[0];
  const float* w_attn = (const float*)d_in[1];
  const float* b_attn = (const float*)d_in[2];
  const float* w_proj = (const float*)d_in[3];
  const float* b_proj = (const float*)d_in[4];
  float* out = (float*)d_out;

  char* ws = (char*)d_ws;
  unsigned short* xb  = (unsigned short*)(ws + 0);          // 8192x1024 bf16; reused as Y
  unsigned short* wta = (unsigned short*)(ws + 16777216);   // 3072x1024 bf16
  unsigned short* wtp = (unsigned short*)(ws + 23068672);   // 1024x1024 bf16
  unsigned short* qb  = (unsigned short*)(ws + 25165824);   // q,k: [64][2048][64]; vt: [64][64][2048]
  unsigned short* yb  = xb;

  cast_f32_bf16<<<(MROWS * CCH) / 1024, 256, 0, stream>>>(x, xb, MROWS * CCH);
  transpose_cast<<<(CCH * 3 * CCH + 255) / 256, 256, 0, stream>>>(w_attn, wta, CCH, 3 * CCH);
  transpose_cast<<<(CCH * CCH + 255) / 256, 256, 0, stream>>>(w_proj, wtp, CCH, CCH);

  {
    dim3 grid(3 * CCH / 128, MROWS / 128);
    gemm_bt<1><<<grid, 256, 0, stream>>>(xb, wta, b_attn, nullptr, qb, MROWS, 3 * CCH, CCH);
  }
  {
    dim3 grid(16, BB * NHH);   // 64 strip-pairs / 4 waves, 64 bh
    attn_kernel<<<grid, 256, 0, stream>>>(qb, qb + (size_t)QKV_ELEMS, qb + 2 * (size_t)QKV_ELEMS, yb);
  }
  {
    dim3 grid(CCH / 128, MROWS / 128);
    gemm_bt<0><<<grid, 256, 0, stream>>>(yb, wtp, b_proj, out, nullptr, MROWS, CCH, CCH);
  }
}

// Round 8
// 296.752 us; speedup vs baseline: 2.0299x; 1.3035x over previous
//
#include <hip/hip_runtime.h>
#include <hip/hip_bf16.h>

// Problem constants
#define BB 4
#define TT 2048
#define CCH 1024
#define NHH 16
#define HSS 64
#define MROWS (BB * TT)            // 8192
#define QKV_ELEMS (64 * 2048 * 64) // per-tensor elems = 8388608

typedef __attribute__((ext_vector_type(8))) short short8;
typedef __attribute__((ext_vector_type(4))) float f32x4;

#define CVTPK(d, a, b) asm("v_cvt_pk_bf16_f32 %0, %1, %2" : "=v"(d) : "v"(a), "v"(b))

static __device__ __forceinline__ unsigned short bf16_of(float f) {
  union { float f; unsigned u; } v; v.f = f;
  unsigned u = v.u;
  return (unsigned short)((u + 0x7FFFu + ((u >> 16) & 1u)) >> 16);
}

// ---------------- cast kernels ----------------
__global__ __launch_bounds__(256) void cast_f32_bf16(const float* __restrict__ in,
                                                     unsigned short* __restrict__ out, int n) {
  int i = (blockIdx.x * 256 + threadIdx.x) * 4;
  if (i < n) {
    float4 f = *reinterpret_cast<const float4*>(in + i);
    ushort4 o;
    o.x = bf16_of(f.x); o.y = bf16_of(f.y); o.z = bf16_of(f.z); o.w = bf16_of(f.w);
    *reinterpret_cast<ushort4*>(out + i) = o;
  }
}

// in: [K][N] f32 row-major -> out: [N][K] bf16 row-major
__global__ __launch_bounds__(256) void transpose_cast(const float* __restrict__ in,
                                                      unsigned short* __restrict__ out,
                                                      int K, int N) {
  int idx = blockIdx.x * 256 + threadIdx.x;
  if (idx < K * N) {
    int k = idx / N;
    int n = idx - k * N;
    out[(size_t)n * K + k] = bf16_of(in[idx]);
  }
}

// ---------------- GEMM: C = A[M,K] @ Bt[N,K]^T + bias (verified R1-R3) ----------------
template <int MODE>
__global__ __launch_bounds__(256) void gemm_bt(const unsigned short* __restrict__ A,
                                               const unsigned short* __restrict__ Bt,
                                               const float* __restrict__ bias,
                                               float* __restrict__ outF,
                                               unsigned short* __restrict__ outQKV,
                                               int M, int N, int K) {
  __shared__ unsigned short As[128 * 32];
  __shared__ unsigned short Bs[128 * 32];
  int tid = threadIdx.x;
  int w = tid >> 6, lane = tid & 63;
  int g = lane >> 4, r16 = lane & 15;
  int wr = w >> 1, wc = w & 1;
  int m0 = blockIdx.y * 128, n0 = blockIdx.x * 128;
  int lrow = lane >> 2;
  int lcol = (lane & 3) * 8;

  f32x4 zero = {0.f, 0.f, 0.f, 0.f};
  f32x4 acc[4][4];
#pragma unroll
  for (int i = 0; i < 4; ++i)
#pragma unroll
    for (int n = 0; n < 4; ++n) acc[i][n] = zero;

  for (int kt = 0; kt < K; kt += 32) {
#pragma unroll
    for (int c = 0; c < 2; ++c) {
      int rg = w * 32 + c * 16;
      __builtin_amdgcn_global_load_lds(
          (const __attribute__((address_space(1))) void*)(&A[(size_t)(m0 + rg + lrow) * K + kt + lcol]),
          (__attribute__((address_space(3))) void*)(&As[rg * 32]), 16, 0, 0);
      __builtin_amdgcn_global_load_lds(
          (const __attribute__((address_space(1))) void*)(&Bt[(size_t)(n0 + rg + lrow) * K + kt + lcol]),
          (__attribute__((address_space(3))) void*)(&Bs[rg * 32]), 16, 0, 0);
    }
    __syncthreads();
    short8 af[4], bfr[4];
#pragma unroll
    for (int i = 0; i < 4; ++i)
      af[i] = *reinterpret_cast<const short8*>(&As[(wr * 64 + i * 16 + r16) * 32 + g * 8]);
#pragma unroll
    for (int i = 0; i < 4; ++i)
      bfr[i] = *reinterpret_cast<const short8*>(&Bs[(wc * 64 + i * 16 + r16) * 32 + g * 8]);
#pragma unroll
    for (int i = 0; i < 4; ++i)
#pragma unroll
      for (int n = 0; n < 4; ++n)
        acc[i][n] = __builtin_amdgcn_mfma_f32_16x16x32_bf16(af[i], bfr[n], acc[i][n], 0, 0, 0);
    __syncthreads();
  }

#pragma unroll
  for (int i = 0; i < 4; ++i)
#pragma unroll
    for (int n = 0; n < 4; ++n)
#pragma unroll
      for (int j = 0; j < 4; ++j) {
        int row = m0 + wr * 64 + i * 16 + g * 4 + j;
        int col = n0 + wc * 64 + n * 16 + r16;
        float val = acc[i][n][j] + bias[col];
        if (MODE == 0) {
          outF[(size_t)row * N + col] = val;
        } else {
          int which = col >> 10, c = col & 1023;
          int h = c >> 6, d = c & 63;
          int b = row >> 11, t = row & 2047;
          if (which == 2) {
            outQKV[2 * (size_t)QKV_ELEMS +
                   (((size_t)(b * 16 + h) * 64 + d) * 2048 + t)] = bf16_of(val);
          } else {
            if (which == 0) val *= 0.125f;   // fold 1/sqrt(HS) into Q (exact pow2)
            outQKV[(size_t)which * QKV_ELEMS +
                   (((size_t)(b * 16 + h) * 2048 + t) * 64 + d)] = bf16_of(val);
          }
        }
      }
}

// ---------------- causal flash attention: 64-row q-block per wave ----------------
// Swapped QK^T on 16x16x32 (R6-verified math). One K/V tile load feeds 4
// independent strip chains (in-wave ILP). No LDS arrays, no barriers.
struct Frags { short8 kf0[2], kf1[2], vf[4]; };

static __device__ __forceinline__ void load_frags(Frags& f, int key0, int r16, int g4,
                                                  const unsigned short* __restrict__ Kp,
                                                  const unsigned short* __restrict__ Vp) {
#pragma unroll
  for (int c = 0; c < 2; ++c)
    f.kf0[c] = *reinterpret_cast<const short8*>(&Kp[(size_t)(key0 + r16) * 64 + c * 32 + g4 * 8]);
#pragma unroll
  for (int c = 0; c < 2; ++c)
    f.kf1[c] = *reinterpret_cast<const short8*>(&Kp[(size_t)(key0 + 16 + r16) * 64 + c * 32 + g4 * 8]);
#pragma unroll
  for (int dblk = 0; dblk < 4; ++dblk)
    f.vf[dblk] = *reinterpret_cast<const short8*>(&Vp[(size_t)(dblk * 16 + r16) * TT + key0 + g4 * 8]);
}

// MODE 0: full 32-key tile. MODE 1: kb0 full + kb1 diag. MODE 2: kb0 diag only
// (kb1 contributions vanish because pf packs p1=0; full-tile V data is harmless).
template <int MODE>
static __device__ __forceinline__ void compute_tile(const Frags& f, int r16, int g4,
                                                    const short8 qf[2], f32x4 o[4],
                                                    float& m, float& lsum) {
  f32x4 zero = {0.f, 0.f, 0.f, 0.f};
  f32x4 s0 = zero, s1 = zero;
  __builtin_amdgcn_s_setprio(1);
  s0 = __builtin_amdgcn_mfma_f32_16x16x32_bf16(f.kf0[0], qf[0], s0, 0, 0, 0);
  s0 = __builtin_amdgcn_mfma_f32_16x16x32_bf16(f.kf0[1], qf[1], s0, 0, 0, 0);
  if (MODE != 2) {
    s1 = __builtin_amdgcn_mfma_f32_16x16x32_bf16(f.kf1[0], qf[0], s1, 0, 0, 0);
    s1 = __builtin_amdgcn_mfma_f32_16x16x32_bf16(f.kf1[1], qf[1], s1, 0, 0, 0);
  }
  __builtin_amdgcn_s_setprio(0);

  if (MODE == 2) {
#pragma unroll
    for (int r = 0; r < 4; ++r)
      if (g4 * 4 + r > r16) s0[r] = -1e30f;
  }
  if (MODE == 1) {
#pragma unroll
    for (int r = 0; r < 4; ++r)
      if (g4 * 4 + r > r16) s1[r] = -1e30f;
  }

  float om = fmaxf(fmaxf(s0[0], s0[1]), fmaxf(s0[2], s0[3]));
  if (MODE != 2)
    om = fmaxf(om, fmaxf(fmaxf(s1[0], s1[1]), fmaxf(s1[2], s1[3])));
  om = fmaxf(om, __shfl_xor(om, 16));
  om = fmaxf(om, __shfl_xor(om, 32));
  float mn = fmaxf(m, om);
  float alpha = __expf(m - mn);
  m = mn;

  float p0[4], p1[4];
#pragma unroll
  for (int r = 0; r < 4; ++r) {
    p0[r] = __expf(s0[r] - mn);
    p1[r] = (MODE == 2) ? 0.f : __expf(s1[r] - mn);
  }
  float rs = (p0[0] + p0[1]) + (p0[2] + p0[3]);
  if (MODE != 2) rs += (p1[0] + p1[1]) + (p1[2] + p1[3]);
  rs += __shfl_xor(rs, 16);
  rs += __shfl_xor(rs, 32);
  lsum = lsum * alpha + rs;
#pragma unroll
  for (int dblk = 0; dblk < 4; ++dblk)
#pragma unroll
    for (int r = 0; r < 4; ++r) o[dblk][r] *= alpha;

  int w00, w01, w10, w11;
  CVTPK(w00, p0[0], p0[1]); CVTPK(w01, p0[2], p0[3]);
  CVTPK(w10, p1[0], p1[1]); CVTPK(w11, p1[2], p1[3]);

  int srcA = r16 + 32 * (g4 & 1);
  int srcB = srcA + 16;
  int a0 = __shfl(w00, srcA, 64), b0 = __shfl(w10, srcA, 64);
  int a1 = __shfl(w01, srcA, 64), b1 = __shfl(w11, srcA, 64);
  int a2 = __shfl(w00, srcB, 64), b2 = __shfl(w10, srcB, 64);
  int a3 = __shfl(w01, srcB, 64), b3 = __shfl(w11, srcB, 64);
  bool hi = (g4 >> 1);
  union { int w[4]; short8 s8; } pf;
  pf.w[0] = hi ? b0 : a0;
  pf.w[1] = hi ? b1 : a1;
  pf.w[2] = hi ? b2 : a2;
  pf.w[3] = hi ? b3 : a3;

  __builtin_amdgcn_s_setprio(1);
#pragma unroll
  for (int dblk = 0; dblk < 4; ++dblk)
    o[dblk] = __builtin_amdgcn_mfma_f32_16x16x32_bf16(f.vf[dblk], pf.s8, o[dblk], 0, 0, 0);
  __builtin_amdgcn_s_setprio(0);
}

__global__ __launch_bounds__(64, 2) void attn_kernel(const unsigned short* __restrict__ Qm,
                                                     const unsigned short* __restrict__ Km,
                                                     const unsigned short* __restrict__ Vt,
                                                     unsigned short* __restrict__ Y) {
  int lane = threadIdx.x;
  int r16 = lane & 15, g4 = lane >> 4;
  int bh = blockIdx.y;
  int a = (int)(gridDim.x - 1 - blockIdx.x); // heavy-first
  int Q0 = a * 64;
  const unsigned short* Qp = Qm + (size_t)bh * TT * HSS;
  const unsigned short* Kp = Km + (size_t)bh * TT * HSS;
  const unsigned short* Vp = Vt + (size_t)bh * HSS * TT;

  // Q fragments for 4 strips (rows Q0+16ss+r16)
  short8 qf[4][2];
#pragma unroll
  for (int ss = 0; ss < 4; ++ss)
#pragma unroll
    for (int c = 0; c < 2; ++c)
      qf[ss][c] = *reinterpret_cast<const short8*>(
          &Qp[(size_t)(Q0 + ss * 16 + r16) * 64 + c * 32 + g4 * 8]);

  f32x4 o[4][4];
#pragma unroll
  for (int ss = 0; ss < 4; ++ss)
#pragma unroll
    for (int dblk = 0; dblk < 4; ++dblk) o[ss][dblk] = f32x4{0.f, 0.f, 0.f, 0.f};
  float m[4] = {-1e30f, -1e30f, -1e30f, -1e30f};
  float l[4] = {0.f, 0.f, 0.f, 0.f};

  Frags F;
  // tiles full for all 4 strips: t = 0 .. 2a-1
  int nfull = a * 2;
  for (int t = 0; t < nfull; ++t) {
    load_frags(F, t << 5, r16, g4, Kp, Vp);
#pragma unroll
    for (int ss = 0; ss < 4; ++ss)
      compute_tile<0>(F, r16, g4, qf[ss], o[ss], m[ss], l[ss]);
  }
  // tile 2a (key0 = Q0): ss0 diag(M2), ss1 M1, ss2/ss3 full
  load_frags(F, Q0, r16, g4, Kp, Vp);
  compute_tile<2>(F, r16, g4, qf[0], o[0], m[0], l[0]);
  compute_tile<1>(F, r16, g4, qf[1], o[1], m[1], l[1]);
  compute_tile<0>(F, r16, g4, qf[2], o[2], m[2], l[2]);
  compute_tile<0>(F, r16, g4, qf[3], o[3], m[3], l[3]);
  // tile 2a+1 (key0 = Q0+32): ss2 M2, ss3 M1
  load_frags(F, Q0 + 32, r16, g4, Kp, Vp);
  compute_tile<2>(F, r16, g4, qf[2], o[2], m[2], l[2]);
  compute_tile<1>(F, r16, g4, qf[3], o[3], m[3], l[3]);

  // epilogue
  int b = bh >> 4, h = bh & 15;
#pragma unroll
  for (int ss = 0; ss < 4; ++ss) {
    float inv = 1.0f / l[ss];
    unsigned short* yrow = Y + ((size_t)(b * TT + Q0 + ss * 16 + r16) * CCH) + h * 64;
#pragma unroll
    for (int dblk = 0; dblk < 4; ++dblk) {
      float v0 = o[ss][dblk][0] * inv, v1 = o[ss][dblk][1] * inv;
      float v2 = o[ss][dblk][2] * inv, v3 = o[ss][dblk][3] * inv;
      int wa, wb;
      CVTPK(wa, v0, v1);
      CVTPK(wb, v2, v3);
      int2 pk; pk.x = wa; pk.y = wb;
      *reinterpret_cast<int2*>(&yrow[dblk * 16 + g4 * 4]) = pk;
    }
  }
}

// ---------------- host ----------------
extern "C" void kernel_launch(void* const* d_in, const int* in_sizes, int n_in,
                              void* d_out, int out_size, void* d_ws, size_t ws_size,
                              hipStream_t stream) {
  const float* x      = (const float*)d_in[0];
  const float* w_attn = (const float*)d_in[1];
  const float* b_attn = (const float*)d_in[2];
  const float* w_proj = (const float*)d_in[3];
  const float* b_proj = (const float*)d_in[4];
  float* out = (float*)d_out;

  char* ws = (char*)d_ws;
  unsigned short* xb  = (unsigned short*)(ws + 0);          // 8192x1024 bf16; reused as Y
  unsigned short* wta = (unsigned short*)(ws + 16777216);   // 3072x1024 bf16
  unsigned short* wtp = (unsigned short*)(ws + 23068672);   // 1024x1024 bf16
  unsigned short* qb  = (unsigned short*)(ws + 25165824);   // q,k: [64][2048][64]; vt: [64][64][2048]
  unsigned short* yb  = xb;

  cast_f32_bf16<<<(MROWS * CCH) / 1024, 256, 0, stream>>>(x, xb, MROWS * CCH);
  transpose_cast<<<(CCH * 3 * CCH + 255) / 256, 256, 0, stream>>>(w_attn, wta, CCH, 3 * CCH);
  transpose_cast<<<(CCH * CCH + 255) / 256, 256, 0, stream>>>(w_proj, wtp, CCH, CCH);

  {
    dim3 grid(3 * CCH / 128, MROWS / 128);
    gemm_bt<1><<<grid, 256, 0, stream>>>(xb, wta, b_attn, nullptr, qb, MROWS, 3 * CCH, CCH);
  }
  {
    dim3 grid(TT / 64, BB * NHH);   // 32 q-blocks x 64 bh, 1 wave each
    attn_kernel<<<grid, 64, 0, stream>>>(qb, qb + (size_t)QKV_ELEMS, qb + 2 * (size_t)QKV_ELEMS, yb);
  }
  {
    dim3 grid(CCH / 128, MROWS / 128);
    gemm_bt<0><<<grid, 256, 0, stream>>>(yb, wtp, b_proj, out, nullptr, MROWS, CCH, CCH);
  }
}